// Round 7
// baseline (1316.421 us; speedup 1.0000x reference)
//
#include <hip/hip_runtime.h>

// ---------------------------------------------------------------------------
// Kernel A: i_x[t,b,n] = sum_k x[t,b,k] * w_in[k,n]
// Plain fp32 vector GEMM: M = T*B = 128000, K = 256, N = 256.  (~112 TF)
// ---------------------------------------------------------------------------
__global__ __launch_bounds__(256) void gemm_xw(const float* __restrict__ X,
                                               const float* __restrict__ W,
                                               float* __restrict__ Y,
                                               int M) {
    __shared__ float As[32][132];
    __shared__ float Bs[32][128];

    const int tid = threadIdx.x;
    const int mb = blockIdx.x >> 1;
    const int nb = blockIdx.x & 1;
    const int m0 = mb << 7;
    const int n0 = nb << 7;
    const int tr = (tid >> 4) << 3;
    const int tc = (tid & 15) << 3;

    float acc[8][8];
#pragma unroll
    for (int i = 0; i < 8; ++i)
#pragma unroll
        for (int j = 0; j < 8; ++j) acc[i][j] = 0.f;

    for (int kb = 0; kb < 256; kb += 32) {
#pragma unroll
        for (int i = 0; i < 4; ++i) {
            int f = tid + (i << 8);
            int row = f >> 3, kq = f & 7;
            float4 a = *(const float4*)(X + (size_t)(m0 + row) * 256 + kb + (kq << 2));
            As[(kq << 2) + 0][row] = a.x;
            As[(kq << 2) + 1][row] = a.y;
            As[(kq << 2) + 2][row] = a.z;
            As[(kq << 2) + 3][row] = a.w;
            int rowb = f >> 5, cq = f & 31;
            *(float4*)&Bs[rowb][cq << 2] =
                *(const float4*)(W + (size_t)(kb + rowb) * 256 + n0 + (cq << 2));
        }
        __syncthreads();
#pragma unroll
        for (int k = 0; k < 32; ++k) {
            float a[8], b[8];
            *(float4*)&a[0] = *(const float4*)&As[k][tr];
            *(float4*)&a[4] = *(const float4*)&As[k][tr + 4];
            *(float4*)&b[0] = *(const float4*)&Bs[k][tc];
            *(float4*)&b[4] = *(const float4*)&Bs[k][tc + 4];
#pragma unroll
            for (int i = 0; i < 8; ++i)
#pragma unroll
                for (int j = 0; j < 8; ++j)
                    acc[i][j] = fmaf(a[i], b[j], acc[i][j]);
        }
        __syncthreads();
    }
#pragma unroll
    for (int i = 0; i < 8; ++i) {
        float* yp = Y + (size_t)(m0 + tr + i) * 256 + n0 + tc;
        *(float4*)yp = make_float4(acc[i][0], acc[i][1], acc[i][2], acc[i][3]);
        *(float4*)(yp + 4) = make_float4(acc[i][4], acc[i][5], acc[i][6], acc[i][7]);
    }
}

// ---------------------------------------------------------------------------
// DIAGNOSTIC 1: lif_nomem — full step math + ballots + branch skeleton,
// ZERO global memory in the loop (input synthesized in registers).
// Runs `steps` iterations (2000 = 2x real) so if compute is the wall it
// dominates the rocprof table. Writes a fold of the state to d_ws only.
// ---------------------------------------------------------------------------
__global__ __launch_bounds__(64) void lif_nomem(const float* __restrict__ wrec,
                                                const float* __restrict__ z0,
                                                const float* __restrict__ v0,
                                                const float* __restrict__ t0,
                                                float* __restrict__ ws,
                                                int steps, int B) {
    const int b = blockIdx.x;
    const int lane = threadIdx.x;
    const int nbase = lane << 2;
    const size_t sb = (size_t)b * 256 + nbase;

    float4 v4 = *(const float4*)(v0 + sb);
    float4 t4 = *(const float4*)(t0 + sb);
    float4 z4 = *(const float4*)(z0 + sb);
    float v[4] = {v4.x, v4.y, v4.z, v4.w};
    float t[4] = {t4.x, t4.y, t4.z, t4.w};
    float z[4] = {z4.x, z4.y, z4.z, z4.w};

    unsigned long long mk0 = __ballot(z[0] != 0.f);
    unsigned long long mk1 = __ballot(z[1] != 0.f);
    unsigned long long mk2 = __ballot(z[2] != 0.f);
    unsigned long long mk3 = __ballot(z[3] != 0.f);

    auto wload = [&](int row) -> float4 {
        const float* wp = wrec + ((size_t)row << 8) + nbase;
        float4 w4;
        asm volatile("global_load_dwordx4 %0, %1, off\n\ts_waitcnt vmcnt(0)"
                     : "=v"(w4) : "v"(wp) : "memory");
        return w4;
    };

    for (int s = 0; s < steps; ++s) {
        float ir[4] = {0.f, 0.f, 0.f, 0.f};
        if (mk0 | mk1 | mk2 | mk3) {   // never taken after warmup (no spikes)
            unsigned long long mm;
            mm = mk0;
            while (mm) { int j = __builtin_ctzll(mm); mm &= mm - 1;
                float4 w = wload((j << 2) + 0);
                ir[0] += w.x; ir[1] += w.y; ir[2] += w.z; ir[3] += w.w; }
            mm = mk1;
            while (mm) { int j = __builtin_ctzll(mm); mm &= mm - 1;
                float4 w = wload((j << 2) + 1);
                ir[0] += w.x; ir[1] += w.y; ir[2] += w.z; ir[3] += w.w; }
            mm = mk2;
            while (mm) { int j = __builtin_ctzll(mm); mm &= mm - 1;
                float4 w = wload((j << 2) + 2);
                ir[0] += w.x; ir[1] += w.y; ir[2] += w.z; ir[3] += w.w; }
            mm = mk3;
            while (mm) { int j = __builtin_ctzll(mm); mm &= mm - 1;
                float4 w = wload((j << 2) + 3);
                ir[0] += w.x; ir[1] += w.y; ir[2] += w.z; ir[3] += w.w; }
        }
        float nzf[4];
#pragma unroll
        for (int c = 0; c < 4; ++c) {
            float i_in = fmaf(v[c], 0.25f, 0.3f) + ir[c];   // synthetic input
            float h = (i_in != 0.f) ? 1.f : 0.f;
            float nt = t[c] + (1.f - h);
            float nv = (z[c] != 0.f) ? 0.f : v[c];
            nv = fmaxf(nv, -1.f);
            float cap = __builtin_amdgcn_exp2f(fabsf(nv)) - 1.f;
            float arg = fminf(h * (nt + 1.f), cap);
            float L = __builtin_amdgcn_logf((1e-5f + arg) + 1.f);
            float sgn = (nv > 0.f) ? 1.f : ((nv < 0.f) ? -1.f : 0.f);
            nv = fmaf(-sgn, L, nv);
            nv = nv + i_in;
            nt = nt * (1.f - h);
            float zf = ((nv - 0.5f) > 0.f) ? 1.f : 0.f;
            v[c] = nv; t[c] = nt; z[c] = zf; nzf[c] = zf;
        }
        mk0 = __ballot(nzf[0] != 0.f);
        mk1 = __ballot(nzf[1] != 0.f);
        mk2 = __ballot(nzf[2] != 0.f);
        mk3 = __ballot(nzf[3] != 0.f);
    }
    unsigned fold = 0;
#pragma unroll
    for (int c = 0; c < 4; ++c)
        fold ^= __float_as_uint(v[c]) ^ __float_as_uint(t[c]) ^ __float_as_uint(z[c]);
    ws[b * 64 + lane] = __uint_as_float(fold);
}

// ---------------------------------------------------------------------------
// DIAGNOSTIC 2: lif_nostore — real ix chunk loads + real gather + full
// compute (identical structure to lif_seq), but NO per-chunk output stores:
// outputs XOR-fold into registers, one store at the end (to d_ws).
// Must run BEFORE lif_seq (lif_seq overwrites ix).
// ---------------------------------------------------------------------------
__global__ __launch_bounds__(64) void lif_nostore(const float* __restrict__ ix,
                                                  const float* __restrict__ wrec,
                                                  const float* __restrict__ z0,
                                                  const float* __restrict__ v0,
                                                  const float* __restrict__ t0,
                                                  float* __restrict__ ws,
                                                  int T, int B) {
    const int b = blockIdx.x;
    const int lane = threadIdx.x;
    const int nbase = lane << 2;
    const size_t sb = (size_t)b * 256 + nbase;
    const size_t stride = (size_t)B * 256;

    float4 v4 = *(const float4*)(v0 + sb);
    float4 t4 = *(const float4*)(t0 + sb);
    float4 z4 = *(const float4*)(z0 + sb);
    float v[4] = {v4.x, v4.y, v4.z, v4.w};
    float t[4] = {t4.x, t4.y, t4.z, t4.w};
    float z[4] = {z4.x, z4.y, z4.z, z4.w};

    unsigned long long mk0 = __ballot(z[0] != 0.f);
    unsigned long long mk1 = __ballot(z[1] != 0.f);
    unsigned long long mk2 = __ballot(z[2] != 0.f);
    unsigned long long mk3 = __ballot(z[3] != 0.f);

    const float* ixp = ix + sb;
    unsigned foldz = 0, foldv = 0;

    auto wload = [&](int row) -> float4 {
        const float* wp = wrec + ((size_t)row << 8) + nbase;
        float4 w4;
        asm volatile("global_load_dwordx4 %0, %1, off\n\ts_waitcnt vmcnt(0)"
                     : "=v"(w4) : "v"(wp) : "memory");
        return w4;
    };

    auto step = [&](float4 r) {
        float ir[4] = {0.f, 0.f, 0.f, 0.f};
        if (mk0 | mk1 | mk2 | mk3) {
            unsigned long long mm;
            mm = mk0;
            while (mm) { int j = __builtin_ctzll(mm); mm &= mm - 1;
                float4 w = wload((j << 2) + 0);
                ir[0] += w.x; ir[1] += w.y; ir[2] += w.z; ir[3] += w.w; }
            mm = mk1;
            while (mm) { int j = __builtin_ctzll(mm); mm &= mm - 1;
                float4 w = wload((j << 2) + 1);
                ir[0] += w.x; ir[1] += w.y; ir[2] += w.z; ir[3] += w.w; }
            mm = mk2;
            while (mm) { int j = __builtin_ctzll(mm); mm &= mm - 1;
                float4 w = wload((j << 2) + 2);
                ir[0] += w.x; ir[1] += w.y; ir[2] += w.z; ir[3] += w.w; }
            mm = mk3;
            while (mm) { int j = __builtin_ctzll(mm); mm &= mm - 1;
                float4 w = wload((j << 2) + 3);
                ir[0] += w.x; ir[1] += w.y; ir[2] += w.z; ir[3] += w.w; }
        }
        float rr[4] = {r.x, r.y, r.z, r.w};
        float nzf[4];
#pragma unroll
        for (int c = 0; c < 4; ++c) {
            float i_in = rr[c] + ir[c];
            float h = (i_in != 0.f) ? 1.f : 0.f;
            float nt = t[c] + (1.f - h);
            float nv = (z[c] != 0.f) ? 0.f : v[c];
            nv = fmaxf(nv, -1.f);
            float cap = __builtin_amdgcn_exp2f(fabsf(nv)) - 1.f;
            float arg = fminf(h * (nt + 1.f), cap);
            float L = __builtin_amdgcn_logf((1e-5f + arg) + 1.f);
            float sgn = (nv > 0.f) ? 1.f : ((nv < 0.f) ? -1.f : 0.f);
            nv = fmaf(-sgn, L, nv);
            nv = nv + i_in;
            nt = nt * (1.f - h);
            float zf = ((nv - 0.5f) > 0.f) ? 1.f : 0.f;
            v[c] = nv; t[c] = nt; z[c] = zf; nzf[c] = zf;
            foldz ^= __float_as_uint(zf);
            foldv ^= __float_as_uint(nv);
        }
        mk0 = __ballot(nzf[0] != 0.f);
        mk1 = __ballot(nzf[1] != 0.f);
        mk2 = __ballot(nzf[2] != 0.f);
        mk3 = __ballot(nzf[3] != 0.f);
    };

    float4 iA[8], iB[8];
    auto loadChunk = [&](float4 (&ib)[8], int c0) {
#pragma unroll
        for (int u = 0; u < 8; ++u) {
            int r = c0 + u;
            r = (r < T) ? r : T - 1;
            ib[u] = *(const float4*)(ixp + (size_t)r * stride);
        }
    };
    auto runChunk = [&](float4 (&ib)[8]) {
#pragma unroll
        for (int u = 0; u < 8; ++u) step(ib[u]);
    };

    loadChunk(iA, 0);
    int c = 0;
    while (c + 16 <= T) {
        loadChunk(iB, c + 8);
        runChunk(iA);
        loadChunk(iA, c + 16);
        runChunk(iB);
        c += 16;
    }
    if (c + 8 <= T) { runChunk(iA); c += 8; }
    for (int ts = c; ts < T; ++ts) {
        float4 r = *(const float4*)(ixp + (size_t)ts * stride);
        step(r);
    }
    ws[8192 + b * 64 + lane] = __uint_as_float(foldz ^ (foldv * 2654435761u));
}

// ---------------------------------------------------------------------------
// Kernel B (REAL, byte-identical to R6): sequential scan, 1 wave/sample,
// chunked double-buffered ix loads, burst stores, fused-asm gather.
// ---------------------------------------------------------------------------
__global__ __launch_bounds__(64) void lif_seq(const float* __restrict__ ix,
                                              const float* __restrict__ wrec,
                                              const float* __restrict__ z0,
                                              const float* __restrict__ v0,
                                              const float* __restrict__ t0,
                                              float* __restrict__ zs,
                                              float* __restrict__ vs,
                                              int T, int B) {
    const int b = blockIdx.x;
    const int lane = threadIdx.x;
    const int nbase = lane << 2;
    const size_t sb = (size_t)b * 256 + nbase;
    const size_t stride = (size_t)B * 256;

    float4 v4 = *(const float4*)(v0 + sb);
    float4 t4 = *(const float4*)(t0 + sb);
    float4 z4 = *(const float4*)(z0 + sb);
    float v[4] = {v4.x, v4.y, v4.z, v4.w};
    float t[4] = {t4.x, t4.y, t4.z, t4.w};
    float z[4] = {z4.x, z4.y, z4.z, z4.w};

    unsigned long long mk0 = __ballot(z[0] != 0.f);
    unsigned long long mk1 = __ballot(z[1] != 0.f);
    unsigned long long mk2 = __ballot(z[2] != 0.f);
    unsigned long long mk3 = __ballot(z[3] != 0.f);

    const float* ixp = ix + sb;

    auto wload = [&](int row) -> float4 {
        const float* wp = wrec + ((size_t)row << 8) + nbase;
        float4 w4;
        asm volatile("global_load_dwordx4 %0, %1, off\n\ts_waitcnt vmcnt(0)"
                     : "=v"(w4) : "v"(wp) : "memory");
        return w4;
    };

    auto step = [&](float4 r, float4& zo4, float4& vo4) {
        float ir[4] = {0.f, 0.f, 0.f, 0.f};
        if (mk0 | mk1 | mk2 | mk3) {
            unsigned long long mm;
            mm = mk0;
            while (mm) { int j = __builtin_ctzll(mm); mm &= mm - 1;
                float4 w = wload((j << 2) + 0);
                ir[0] += w.x; ir[1] += w.y; ir[2] += w.z; ir[3] += w.w; }
            mm = mk1;
            while (mm) { int j = __builtin_ctzll(mm); mm &= mm - 1;
                float4 w = wload((j << 2) + 1);
                ir[0] += w.x; ir[1] += w.y; ir[2] += w.z; ir[3] += w.w; }
            mm = mk2;
            while (mm) { int j = __builtin_ctzll(mm); mm &= mm - 1;
                float4 w = wload((j << 2) + 2);
                ir[0] += w.x; ir[1] += w.y; ir[2] += w.z; ir[3] += w.w; }
            mm = mk3;
            while (mm) { int j = __builtin_ctzll(mm); mm &= mm - 1;
                float4 w = wload((j << 2) + 3);
                ir[0] += w.x; ir[1] += w.y; ir[2] += w.z; ir[3] += w.w; }
        }

        float rr[4] = {r.x, r.y, r.z, r.w};
        float nzf[4], nvf[4];
#pragma unroll
        for (int c = 0; c < 4; ++c) {
            float i_in = rr[c] + ir[c];
            float h = (i_in != 0.f) ? 1.f : 0.f;
            float nt = t[c] + (1.f - h);
            float nv = (z[c] != 0.f) ? 0.f : v[c];
            nv = fmaxf(nv, -1.f);
            float cap = __builtin_amdgcn_exp2f(fabsf(nv)) - 1.f;
            float arg = fminf(h * (nt + 1.f), cap);
            float L = __builtin_amdgcn_logf((1e-5f + arg) + 1.f);
            float sgn = (nv > 0.f) ? 1.f : ((nv < 0.f) ? -1.f : 0.f);
            nv = fmaf(-sgn, L, nv);
            nv = nv + i_in;
            nt = nt * (1.f - h);
            float zf = ((nv - 0.5f) > 0.f) ? 1.f : 0.f;
            v[c] = nv; t[c] = nt; z[c] = zf;
            nvf[c] = nv; nzf[c] = zf;
        }
        mk0 = __ballot(nzf[0] != 0.f);
        mk1 = __ballot(nzf[1] != 0.f);
        mk2 = __ballot(nzf[2] != 0.f);
        mk3 = __ballot(nzf[3] != 0.f);
        zo4 = make_float4(nzf[0], nzf[1], nzf[2], nzf[3]);
        vo4 = make_float4(nvf[0], nvf[1], nvf[2], nvf[3]);
    };

    float4 iA[8], iB[8];
    float4 zo[8], vo[8];

    auto loadChunk = [&](float4 (&ib)[8], int c0) {
#pragma unroll
        for (int u = 0; u < 8; ++u) {
            int r = c0 + u;
            r = (r < T) ? r : T - 1;
            ib[u] = *(const float4*)(ixp + (size_t)r * stride);
        }
    };

    auto runChunk = [&](float4 (&ib)[8], int c0) {
#pragma unroll
        for (int u = 0; u < 8; ++u) step(ib[u], zo[u], vo[u]);
        size_t ob = (size_t)c0 * stride + sb;
#pragma unroll
        for (int u = 0; u < 8; ++u) {
            *(float4*)(zs + ob + (size_t)u * stride) = zo[u];
            *(float4*)(vs + ob + (size_t)u * stride) = vo[u];
        }
    };

    loadChunk(iA, 0);
    int c = 0;
    while (c + 16 <= T) {
        loadChunk(iB, c + 8);
        runChunk(iA, c);
        loadChunk(iA, c + 16);
        runChunk(iB, c + 8);
        c += 16;
    }
    if (c + 8 <= T) {
        runChunk(iA, c);
        c += 8;
    }
    for (int ts = c; ts < T; ++ts) {
        float4 r = *(const float4*)(ixp + (size_t)ts * stride);
        float4 zz, vv;
        step(r, zz, vv);
        size_t o = (size_t)ts * stride + sb;
        *(float4*)(zs + o) = zz;
        *(float4*)(vs + o) = vv;
    }
}

extern "C" void kernel_launch(void* const* d_in, const int* in_sizes, int n_in,
                              void* d_out, int out_size, void* d_ws, size_t ws_size,
                              hipStream_t stream) {
    const float* x    = (const float*)d_in[0];
    const float* z0   = (const float*)d_in[1];
    const float* v0   = (const float*)d_in[2];
    const float* t0   = (const float*)d_in[3];
    const float* w_in = (const float*)d_in[4];
    const float* wrec = (const float*)d_in[5];

    const int n_rec = 256;
    const int B = in_sizes[1] / n_rec;          // 128
    const int nin = in_sizes[4] / n_rec;        // 256
    const int T = in_sizes[0] / (B * nin);      // 1000
    const int M = T * B;                        // 128000

    float* zs = (float*)d_out;
    float* vs = zs + (size_t)T * B * n_rec;
    float* ixbuf = zs;
    float* ws = (float*)d_ws;

    gemm_xw<<<dim3((M / 128) * 2), dim3(256), 0, stream>>>(x, w_in, ixbuf, M);
    // diagnostics (write only to d_ws; nostore must precede lif_seq which
    // overwrites ixbuf)
    lif_nomem<<<dim3(B), dim3(64), 0, stream>>>(wrec, z0, v0, t0, ws, 2000, B);
    lif_nostore<<<dim3(B), dim3(64), 0, stream>>>(ixbuf, wrec, z0, v0, t0, ws, T, B);
    // real
    lif_seq<<<dim3(B), dim3(64), 0, stream>>>(ixbuf, wrec, z0, v0, t0, zs, vs, T, B);
}

// Round 8
// 496.699 us; speedup vs baseline: 2.6503x; 2.6503x over previous
//
#include <hip/hip_runtime.h>

// ---------------------------------------------------------------------------
// Kernel A: i_x[t,b,n] = sum_k x[t,b,k] * w_in[k,n]
// Plain fp32 vector GEMM: M = T*B = 128000, K = 256, N = 256.  (~112 TF)
// ---------------------------------------------------------------------------
__global__ __launch_bounds__(256) void gemm_xw(const float* __restrict__ X,
                                               const float* __restrict__ W,
                                               float* __restrict__ Y,
                                               int M) {
    __shared__ float As[32][132];
    __shared__ float Bs[32][128];

    const int tid = threadIdx.x;
    const int mb = blockIdx.x >> 1;
    const int nb = blockIdx.x & 1;
    const int m0 = mb << 7;
    const int n0 = nb << 7;
    const int tr = (tid >> 4) << 3;
    const int tc = (tid & 15) << 3;

    float acc[8][8];
#pragma unroll
    for (int i = 0; i < 8; ++i)
#pragma unroll
        for (int j = 0; j < 8; ++j) acc[i][j] = 0.f;

    for (int kb = 0; kb < 256; kb += 32) {
#pragma unroll
        for (int i = 0; i < 4; ++i) {
            int f = tid + (i << 8);
            int row = f >> 3, kq = f & 7;
            float4 a = *(const float4*)(X + (size_t)(m0 + row) * 256 + kb + (kq << 2));
            As[(kq << 2) + 0][row] = a.x;
            As[(kq << 2) + 1][row] = a.y;
            As[(kq << 2) + 2][row] = a.z;
            As[(kq << 2) + 3][row] = a.w;
            int rowb = f >> 5, cq = f & 31;
            *(float4*)&Bs[rowb][cq << 2] =
                *(const float4*)(W + (size_t)(kb + rowb) * 256 + n0 + (cq << 2));
        }
        __syncthreads();
#pragma unroll
        for (int k = 0; k < 32; ++k) {
            float a[8], b[8];
            *(float4*)&a[0] = *(const float4*)&As[k][tr];
            *(float4*)&a[4] = *(const float4*)&As[k][tr + 4];
            *(float4*)&b[0] = *(const float4*)&Bs[k][tc];
            *(float4*)&b[4] = *(const float4*)&Bs[k][tc + 4];
#pragma unroll
            for (int i = 0; i < 8; ++i)
#pragma unroll
                for (int j = 0; j < 8; ++j)
                    acc[i][j] = fmaf(a[i], b[j], acc[i][j]);
        }
        __syncthreads();
    }
#pragma unroll
    for (int i = 0; i < 8; ++i) {
        float* yp = Y + (size_t)(m0 + tr + i) * 256 + n0 + tc;
        *(float4*)yp = make_float4(acc[i][0], acc[i][1], acc[i][2], acc[i][3]);
        *(float4*)(yp + 4) = make_float4(acc[i][4], acc[i][5], acc[i][6], acc[i][7]);
    }
}

// ---------------------------------------------------------------------------
// Kernel B: sequential scan. ONE WAVE per sample, 4 neurons/lane. Memory
// structure identical to R6 (chunked dbuf loads, burst stores, fused-asm
// gather). NEW: stage-wise step math for forced 4-chain ILP + trims:
//  - spike state carried as bool lane-masks (sp[]): reset & zf are single
//    cndmasks; ballot of sp is free; spike compare feeds both zf and mask.
//  - sgn handling via copysign(bfi) + zero-select (single-rounding identical
//    to reference's  v - sign(v)*L, signed-zero diffs only -> |diff| = 0).
//  - g(x)=(1e-5+x)+1 commutes with fmin exactly (monotone rounding), so the
//    t-branch candidate cT is computed off the v-critical-path.
//  - h/t machinery: tp1=t+1 exact; argpre in {0, tp1}; ntn = hz?tp1:0.
// ---------------------------------------------------------------------------
__global__ __launch_bounds__(64) void lif_seq(const float* __restrict__ ix,
                                              const float* __restrict__ wrec,
                                              const float* __restrict__ z0,
                                              const float* __restrict__ v0,
                                              const float* __restrict__ t0,
                                              float* __restrict__ zs,
                                              float* __restrict__ vs,
                                              int T, int B) {
    const int b = blockIdx.x;
    const int lane = threadIdx.x;
    const int nbase = lane << 2;
    const size_t sb = (size_t)b * 256 + nbase;
    const size_t stride = (size_t)B * 256;

    float4 v4 = *(const float4*)(v0 + sb);
    float4 t4 = *(const float4*)(t0 + sb);
    float4 z4 = *(const float4*)(z0 + sb);
    float v[4] = {v4.x, v4.y, v4.z, v4.w};
    float t[4] = {t4.x, t4.y, t4.z, t4.w};
    bool sp[4] = {z4.x != 0.f, z4.y != 0.f, z4.z != 0.f, z4.w != 0.f};

    const float* ixp = ix + sb;

    auto wload = [&](int row) -> float4 {
        const float* wp = wrec + ((size_t)row << 8) + nbase;
        float4 w4;
        asm volatile("global_load_dwordx4 %0, %1, off\n\ts_waitcnt vmcnt(0)"
                     : "=v"(w4) : "v"(wp) : "memory");
        return w4;
    };

    constexpr float G0 = 1e-5f + 1.0f;   // g(0) = (1e-5 + 0) + 1, exact

    auto step = [&](float4 r, float4& zo4, float4& vo4) {
        unsigned long long mk0 = __ballot(sp[0]);
        unsigned long long mk1 = __ballot(sp[1]);
        unsigned long long mk2 = __ballot(sp[2]);
        unsigned long long mk3 = __ballot(sp[3]);

        float ir[4] = {0.f, 0.f, 0.f, 0.f};
        if (mk0 | mk1 | mk2 | mk3) {
            unsigned long long mm;
            mm = mk0;
            while (mm) { int j = __builtin_ctzll(mm); mm &= mm - 1;
                float4 w = wload((j << 2) + 0);
                ir[0] += w.x; ir[1] += w.y; ir[2] += w.z; ir[3] += w.w; }
            mm = mk1;
            while (mm) { int j = __builtin_ctzll(mm); mm &= mm - 1;
                float4 w = wload((j << 2) + 1);
                ir[0] += w.x; ir[1] += w.y; ir[2] += w.z; ir[3] += w.w; }
            mm = mk2;
            while (mm) { int j = __builtin_ctzll(mm); mm &= mm - 1;
                float4 w = wload((j << 2) + 2);
                ir[0] += w.x; ir[1] += w.y; ir[2] += w.z; ir[3] += w.w; }
            mm = mk3;
            while (mm) { int j = __builtin_ctzll(mm); mm &= mm - 1;
                float4 w = wload((j << 2) + 3);
                ir[0] += w.x; ir[1] += w.y; ir[2] += w.z; ir[3] += w.w; }
        }

        float rr[4] = {r.x, r.y, r.z, r.w};
        float i_in[4], tp1[4], cT[4], ntn[4], vc[4], E[4], cA[4], L[4], nv[4];
        bool hz[4], spn[4];
        float zf[4];

        // stage-wise: each stage's 4 lanes-of-c are independent
#pragma unroll
        for (int c = 0; c < 4; ++c) i_in[c] = rr[c] + ir[c];
#pragma unroll
        for (int c = 0; c < 4; ++c) hz[c] = (i_in[c] == 0.f);
#pragma unroll
        for (int c = 0; c < 4; ++c) tp1[c] = t[c] + 1.f;
#pragma unroll
        for (int c = 0; c < 4; ++c) cT[c] = hz[c] ? G0 : ((1e-5f + tp1[c]) + 1.f);
#pragma unroll
        for (int c = 0; c < 4; ++c) ntn[c] = hz[c] ? tp1[c] : 0.f;
#pragma unroll
        for (int c = 0; c < 4; ++c) vc[c] = fmaxf(sp[c] ? 0.f : v[c], -1.f);
#pragma unroll
        for (int c = 0; c < 4; ++c) E[c] = __builtin_amdgcn_exp2f(fabsf(vc[c]));
#pragma unroll
        for (int c = 0; c < 4; ++c) cA[c] = (1e-5f + (E[c] - 1.f)) + 1.f;
#pragma unroll
        for (int c = 0; c < 4; ++c) L[c] = __builtin_amdgcn_logf(fminf(cT[c], cA[c]));
#pragma unroll
        for (int c = 0; c < 4; ++c) {
            float Ls = copysignf(L[c], vc[c]);
            float nvp = (vc[c] == 0.f) ? vc[c] : (vc[c] - Ls);
            nv[c] = nvp + i_in[c];
        }
#pragma unroll
        for (int c = 0; c < 4; ++c) spn[c] = (nv[c] > 0.5f);
#pragma unroll
        for (int c = 0; c < 4; ++c) zf[c] = spn[c] ? 1.f : 0.f;
#pragma unroll
        for (int c = 0; c < 4; ++c) { v[c] = nv[c]; t[c] = ntn[c]; sp[c] = spn[c]; }

        zo4 = make_float4(zf[0], zf[1], zf[2], zf[3]);
        vo4 = make_float4(nv[0], nv[1], nv[2], nv[3]);
    };

    float4 iA[8], iB[8];
    float4 zo[8], vo[8];

    auto loadChunk = [&](float4 (&ib)[8], int c0) {
#pragma unroll
        for (int u = 0; u < 8; ++u) {
            int r = c0 + u;
            r = (r < T) ? r : T - 1;
            ib[u] = *(const float4*)(ixp + (size_t)r * stride);
        }
    };

    auto runChunk = [&](float4 (&ib)[8], int c0) {
#pragma unroll
        for (int u = 0; u < 8; ++u) step(ib[u], zo[u], vo[u]);
        size_t ob = (size_t)c0 * stride + sb;
#pragma unroll
        for (int u = 0; u < 8; ++u) {
            *(float4*)(zs + ob + (size_t)u * stride) = zo[u];
            *(float4*)(vs + ob + (size_t)u * stride) = vo[u];
        }
    };

    loadChunk(iA, 0);
    int c = 0;
    while (c + 16 <= T) {
        loadChunk(iB, c + 8);
        runChunk(iA, c);
        loadChunk(iA, c + 16);
        runChunk(iB, c + 8);
        c += 16;
    }
    if (c + 8 <= T) {
        runChunk(iA, c);
        c += 8;
    }
    for (int ts = c; ts < T; ++ts) {
        float4 r = *(const float4*)(ixp + (size_t)ts * stride);
        float4 zz, vv;
        step(r, zz, vv);
        size_t o = (size_t)ts * stride + sb;
        *(float4*)(zs + o) = zz;
        *(float4*)(vs + o) = vv;
    }
}

extern "C" void kernel_launch(void* const* d_in, const int* in_sizes, int n_in,
                              void* d_out, int out_size, void* d_ws, size_t ws_size,
                              hipStream_t stream) {
    const float* x    = (const float*)d_in[0];
    const float* z0   = (const float*)d_in[1];
    const float* v0   = (const float*)d_in[2];
    const float* t0   = (const float*)d_in[3];
    const float* w_in = (const float*)d_in[4];
    const float* wrec = (const float*)d_in[5];

    const int n_rec = 256;
    const int B = in_sizes[1] / n_rec;          // 128
    const int nin = in_sizes[4] / n_rec;        // 256
    const int T = in_sizes[0] / (B * nin);      // 1000
    const int M = T * B;                        // 128000

    float* zs = (float*)d_out;
    float* vs = zs + (size_t)T * B * n_rec;
    float* ixbuf = zs;  // stage x@w_in into the zs region (read-before-write in lif_seq)

    gemm_xw<<<dim3((M / 128) * 2), dim3(256), 0, stream>>>(x, w_in, ixbuf, M);
    lif_seq<<<dim3(B), dim3(64), 0, stream>>>(ixbuf, wrec, z0, v0, t0, zs, vs, T, B);
}